// Round 1
// 506.256 us; speedup vs baseline: 1.0117x; 1.0117x over previous
//
#include <hip/hip_runtime.h>
#include <math.h>

#define NN 100000
#define NE 3200000
#define NF 256
#define NH 128
#define NC 40

#define CH 8192                    // edges per pass-1 block
#define NBLK 391                   // ceil(NE/CH)
#define NBUCK 782                  // ceil(NN/128) buckets of 128 dsts
#define HTOT (NBUCK * NBLK)        // 305762
#define HS1 ((HTOT + 511) / 512)   // 598 scan blocks
#define NTILE 1563                 // ceil(NN/64) gemm row tiles
#define NCP 32                     // padded hwb row: 32 uints = 128 B (aligned line)

typedef unsigned int uint;
typedef short short8 __attribute__((ext_vector_type(8)));
typedef float floatx4 __attribute__((ext_vector_type(4)));

// ---- bf16 helpers (manual, RNE) ------------------------------------------
__device__ __forceinline__ float bflo(uint v) { return __uint_as_float(v << 16); }
__device__ __forceinline__ float bfhi(uint v) { return __uint_as_float(v & 0xffff0000u); }
__device__ __forceinline__ unsigned short f2bf(float f) {
    const uint u = __float_as_uint(f);
    return (unsigned short)((u + 0x7fffu + ((u >> 16) & 1u)) >> 16);
}
__device__ __forceinline__ uint pack2bf(float a, float b) {
    return (uint)f2bf(a) | ((uint)f2bf(b) << 16);
}

union ABfrag { uint u[4]; short8 s; };

// ========== pack W0 (4096 frags) and W1 (768 frags, zero-padded) ==========
// B-frag: n = ntile*16 + (lane&15), k = kstep*32 + (lane>>4)*8 + j
__global__ __launch_bounds__(256) void prep_pack_k(const float* __restrict__ W0,
                                                   const float* __restrict__ W1,
                                                   uint4* __restrict__ W0p,
                                                   uint4* __restrict__ W1p) {
    const int idx = blockIdx.x * 256 + threadIdx.x;
    if (idx < 4096) {  // W0: [kstep 0..7][ntile 0..7][lane]
        const int lane  = idx & 63;
        const int ntile = (idx >> 6) & 7;
        const int kstep = idx >> 9;
        const int n  = ntile * 16 + (lane & 15);
        const int kb = kstep * 32 + (lane >> 4) * 8;
        uint w[4];
#pragma unroll
        for (int ww = 0; ww < 4; ++ww)
            w[ww] = pack2bf(W0[(size_t)(kb + 2 * ww) * NH + n],
                            W0[(size_t)(kb + 2 * ww + 1) * NH + n]);
        W0p[idx] = make_uint4(w[0], w[1], w[2], w[3]);
    } else if (idx < 4096 + 768) {  // W1: [kstep 0..3][ntile 0..2][lane]
        const int i2 = idx - 4096;
        const int lane  = i2 & 63;
        const int ntile = (i2 >> 6) % 3;
        const int kstep = (i2 >> 6) / 3;
        const int n  = ntile * 16 + (lane & 15);
        const int kb = kstep * 32 + (lane >> 4) * 8;
        uint w[4];
#pragma unroll
        for (int ww = 0; ww < 4; ++ww) {
            const float lo = (n < NC) ? W1[(size_t)(kb + 2 * ww) * NC + n] : 0.0f;
            const float hi = (n < NC) ? W1[(size_t)(kb + 2 * ww + 1) * NC + n] : 0.0f;
            w[ww] = pack2bf(lo, hi);
        }
        W1p[i2] = make_uint4(w[0], w[1], w[2], w[3]);
    }
}

// ============================ GEMM1 (MFMA bf16) ===========================
__global__ __launch_bounds__(256) void gemm1_mfma(const float* __restrict__ x,
                                                  const uint4* __restrict__ W0p,
                                                  unsigned short* __restrict__ xwh) {
    __shared__ __align__(16) uint4 sB[4096];  // 64 KB
    for (int i = threadIdx.x; i < 4096; i += 256) sB[i] = W0p[i];
    __syncthreads();

    const int wave = threadIdx.x >> 6;
    const int lane = threadIdx.x & 63;
    const int quad = lane >> 4;
    const int mcol = lane & 15;

    for (int tile = blockIdx.x; tile < NTILE; tile += 512) {
        const int row  = tile * 64 + wave * 16 + mcol;
        const int rowc = min(row, NN - 1);
        const float* xr = x + (size_t)rowc * NF + quad * 8;

        floatx4 acc[8] = {};
        float4 lo = *(const float4*)(xr);
        float4 hi = *(const float4*)(xr + 4);
#pragma unroll
        for (int ks = 0; ks < 8; ++ks) {
            ABfrag a;
            a.u[0] = pack2bf(lo.x, lo.y);
            a.u[1] = pack2bf(lo.z, lo.w);
            a.u[2] = pack2bf(hi.x, hi.y);
            a.u[3] = pack2bf(hi.z, hi.w);
            if (ks < 7) {
                lo = *(const float4*)(xr + (ks + 1) * 32);
                hi = *(const float4*)(xr + (ks + 1) * 32 + 4);
            }
#pragma unroll
            for (int nt = 0; nt < 8; ++nt) {
                ABfrag b;
                const uint4 bw = sB[(ks * 8 + nt) * 64 + lane];
                b.u[0] = bw.x; b.u[1] = bw.y; b.u[2] = bw.z; b.u[3] = bw.w;
                acc[nt] = __builtin_amdgcn_mfma_f32_16x16x32_bf16(a.s, b.s, acc[nt], 0, 0, 0);
            }
        }
        const int rowbase = tile * 64 + wave * 16 + quad * 4;
#pragma unroll
        for (int nt = 0; nt < 8; ++nt) {
#pragma unroll
            for (int r = 0; r < 4; ++r) {
                const int rr = rowbase + r;
                if (rr < NN) xwh[(size_t)rr * NH + nt * 16 + mcol] = f2bf(acc[nt][r]);
            }
        }
    }
}

// ======================= CSR build: pass 1 histogram ======================
__global__ __launch_bounds__(256) void p1hist_k(const int* __restrict__ edst,
                                                int* __restrict__ hmat) {
    __shared__ uint h[NBUCK];
    for (int i = threadIdx.x; i < NBUCK; i += 256) h[i] = 0;
    __syncthreads();
    const int b = blockIdx.x;
    const int e0 = b * CH, e1 = min(NE, e0 + CH);
    for (int e = e0 + threadIdx.x * 4; e + 3 < e1; e += 1024) {  // (e1-e0) % 4 == 0
        const int4 d4 = *(const int4*)(edst + e);
        atomicAdd(&h[((uint)d4.x) >> 7], 1u);
        atomicAdd(&h[((uint)d4.y) >> 7], 1u);
        atomicAdd(&h[((uint)d4.z) >> 7], 1u);
        atomicAdd(&h[((uint)d4.w) >> 7], 1u);
    }
    __syncthreads();
    for (int i = threadIdx.x; i < NBUCK; i += 256)
        hmat[(size_t)i * NBLK + b] = (int)h[i];
}

// ======================= scan of hmat (306K ints) =========================
__global__ __launch_bounds__(512) void hscan1_k(int* __restrict__ hmat,
                                                int* __restrict__ partials) {
    __shared__ int s[512];
    const int t = threadIdx.x;
    const int i = blockIdx.x * 512 + t;
    const int v = (i < HTOT) ? hmat[i] : 0;
    s[t] = v;
    __syncthreads();
#pragma unroll
    for (int off = 1; off < 512; off <<= 1) {
        int a = (t >= off) ? s[t - off] : 0;
        __syncthreads();
        s[t] += a;
        __syncthreads();
    }
    if (i < HTOT) hmat[i] = s[t] - v;          // exclusive, block-local
    if (t == 511) partials[blockIdx.x] = s[t];
}

__global__ __launch_bounds__(1024) void hscan2_k(int* __restrict__ partials, int nb) {
    __shared__ int s[1024];
    const int t = threadIdx.x;
    const int v = (t < nb) ? partials[t] : 0;
    s[t] = v;
    __syncthreads();
#pragma unroll
    for (int off = 1; off < 1024; off <<= 1) {
        int a = (t >= off) ? s[t - off] : 0;
        __syncthreads();
        s[t] += a;
        __syncthreads();
    }
    if (t < nb) partials[t] = s[t] - v;        // exclusive
}

// ======================= pass 1 scatter (partials folded in) ==============
__global__ __launch_bounds__(256) void p1scat_k(const int* __restrict__ esrc,
                                                const int* __restrict__ edst,
                                                const float* __restrict__ ew,
                                                const int* __restrict__ hmat,
                                                const int* __restrict__ partials,
                                                uint2* __restrict__ ep1) {
    __shared__ uint base[NBUCK];
    const int b = blockIdx.x;
    for (int i = threadIdx.x; i < NBUCK; i += 256) {
        const int g = i * NBLK + b;
        base[i] = (uint)(hmat[g] + partials[g >> 9]);
    }
    __syncthreads();
    const int e0 = b * CH, e1 = min(NE, e0 + CH);
    for (int e = e0 + threadIdx.x; e < e1; e += 256) {
        const uint d = (uint)edst[e];
        const uint pos = atomicAdd(&base[d >> 7], 1u);
        ep1[pos] = make_uint2((uint)esrc[e] | ((d & 127u) << 17), __float_as_uint(ew[e]));
    }
}

// ======================= pass 2: in-bucket sort -> CSR + rp ===============
__global__ __launch_bounds__(256) void p2_k(const int* __restrict__ hmat,
                                            const int* __restrict__ partials,
                                            const uint2* __restrict__ ep1,
                                            uint2* __restrict__ ep,
                                            int* __restrict__ rp) {
    const int bk = blockIdx.x;
    const int gb = bk * NBLK;
    const int beg = hmat[gb] + partials[gb >> 9];
    int end;
    if (bk == NBUCK - 1) end = NE;
    else { const int ge = gb + NBLK; end = hmat[ge] + partials[ge >> 9]; }
    __shared__ uint cnt[128];
    __shared__ uint st[128];
    if (threadIdx.x < 128) cnt[threadIdx.x] = 0;
    __syncthreads();
    for (int j = beg + threadIdx.x; j < end; j += 256)
        atomicAdd(&cnt[(ep1[j].x >> 17) & 127u], 1u);
    __syncthreads();
    if (threadIdx.x < 128) st[threadIdx.x] = cnt[threadIdx.x];
    __syncthreads();
#pragma unroll
    for (int off = 1; off < 128; off <<= 1) {
        uint a = 0;
        if (threadIdx.x < 128 && threadIdx.x >= off) a = st[threadIdx.x - off];
        __syncthreads();
        if (threadIdx.x < 128) st[threadIdx.x] += a;
        __syncthreads();
    }
    if (threadIdx.x < 128) {
        const uint start = st[threadIdx.x] - cnt[threadIdx.x];
        const int d = bk * 128 + threadIdx.x;
        if (d < NN) rp[d] = beg + (int)start;
        cnt[threadIdx.x] = (uint)beg + start;
    }
    if (bk == 0 && threadIdx.x == 200) rp[NN] = NE;
    __syncthreads();
    for (int j = beg + threadIdx.x; j < end; j += 256) {
        const uint2 r = ep1[j];
        const uint pos = atomicAdd(&cnt[(r.x >> 17) & 127u], 1u);
        ep[pos] = r;
    }
}

// ================ SpMM1 + bias + L2norm + ReLU -> bf16 h2 =================
// one wave per node; edge metadata forced to SGPRs via readfirstlane.
// Software-pipelined: batch k+1's edge meta is loaded while batch k's
// gathers are in flight, so the meta L2 latency hides under the FMA phase.
__global__ __launch_bounds__(256) void spmm1n_g(const int* __restrict__ rp,
                                                const uint2* __restrict__ ep,
                                                const uint* __restrict__ xwb,
                                                const float* __restrict__ b0,
                                                uint* __restrict__ h2b) {
    const int n = blockIdx.x * 4 + (threadIdx.x >> 6);
    const int t = threadIdx.x & 63;
    const int beg = __builtin_amdgcn_readfirstlane(rp[n]);
    const int end = __builtin_amdgcn_readfirstlane(rp[n + 1]);
    float a0 = 0.f, a1 = 0.f;
    int j = beg;
    const int e8 = end - 7;
    if (j < e8) {
        uint2 e[8];
#pragma unroll
        for (int u = 0; u < 8; ++u) e[u] = ep[j + u];
        for (;;) {
            uint sx[8];
            float w[8];
#pragma unroll
            for (int u = 0; u < 8; ++u) {
                sx[u] = __builtin_amdgcn_readfirstlane(e[u].x) & 0x1FFFFu;
                w[u]  = __uint_as_float(__builtin_amdgcn_readfirstlane(e[u].y));
            }
            uint v[8];
#pragma unroll
            for (int u = 0; u < 8; ++u) v[u] = xwb[(size_t)sx[u] * 64 + t];
            j += 8;
            const bool more = (j < e8);          // wave-uniform
            if (more) {
#pragma unroll
                for (int u = 0; u < 8; ++u) e[u] = ep[j + u];   // prefetch next batch
            }
#pragma unroll
            for (int u = 0; u < 8; ++u) {
                a0 = fmaf(w[u], bflo(v[u]), a0);
                a1 = fmaf(w[u], bfhi(v[u]), a1);
            }
            if (!more) break;
        }
    }
    for (; j < end; ++j) {
        const uint2 e = ep[j];
        const uint sx = __builtin_amdgcn_readfirstlane(e.x) & 0x1FFFFu;
        const float w = __uint_as_float(__builtin_amdgcn_readfirstlane(e.y));
        const uint v = xwb[(size_t)sx * 64 + t];
        a0 = fmaf(w, bflo(v), a0); a1 = fmaf(w, bfhi(v), a1);
    }
    // bias + L2 normalize (wave butterfly) + ReLU, store bf16
    const float2 bb = *(const float2*)(b0 + 2 * t);
    const float v0 = a0 + bb.x, v1 = a1 + bb.y;
    float s = v0 * v0 + v1 * v1;
#pragma unroll
    for (int o = 1; o < 64; o <<= 1) s += __shfl_xor(s, o, 64);
    const float scale = 1.0f / fmaxf(sqrtf(s), 1e-12f);
    h2b[(size_t)n * 64 + t] = pack2bf(fmaxf(v0 * scale, 0.0f), fmaxf(v1 * scale, 0.0f));
}

// ==================== GEMM2 (MFMA bf16, K=128, N=40) ======================
// writes hwb padded to 128 B rows (32 uints = 64 shorts); pad cols zeroed.
__global__ __launch_bounds__(256) void gemm2_mfma(const uint* __restrict__ h2b,
                                                  const uint4* __restrict__ W1p,
                                                  unsigned short* __restrict__ hwh) {
    __shared__ __align__(16) uint4 sB[768];  // 12 KB: [kstep 0..3][ntile 0..2][lane]
    for (int i = threadIdx.x; i < 768; i += 256) sB[i] = W1p[i];
    __syncthreads();

    const int wave = threadIdx.x >> 6;
    const int lane = threadIdx.x & 63;
    const int quad = lane >> 4;
    const int mcol = lane & 15;
    const int row  = blockIdx.x * 64 + wave * 16 + mcol;
    const int rowc = min(row, NN - 1);
    const uint* hr = h2b + (size_t)rowc * 64;

    floatx4 acc[3] = {};
#pragma unroll
    for (int ks = 0; ks < 4; ++ks) {
        ABfrag a;
        const uint4 hv = *(const uint4*)(hr + ks * 16 + quad * 4);
        a.u[0] = hv.x; a.u[1] = hv.y; a.u[2] = hv.z; a.u[3] = hv.w;
#pragma unroll
        for (int nt = 0; nt < 3; ++nt) {
            ABfrag b;
            const uint4 bw = sB[(ks * 3 + nt) * 64 + lane];
            b.u[0] = bw.x; b.u[1] = bw.y; b.u[2] = bw.z; b.u[3] = bw.w;
            acc[nt] = __builtin_amdgcn_mfma_f32_16x16x32_bf16(a.s, b.s, acc[nt], 0, 0, 0);
        }
    }
    const int rowbase = blockIdx.x * 64 + wave * 16 + quad * 4;
#pragma unroll
    for (int nt = 0; nt < 3; ++nt) {
        const int f = nt * 16 + mcol;
#pragma unroll
        for (int r = 0; r < 4; ++r) {
            const int rr = rowbase + r;
            if (rr < NN)
                hwh[(size_t)rr * (2 * NCP) + f] = (f < NC) ? f2bf(acc[nt][r]) : (unsigned short)0;
        }
    }
    // zero pad cols 48..63 (shorts) so padded gathers read zeros
#pragma unroll
    for (int r = 0; r < 4; ++r) {
        const int rr = rowbase + r;
        if (rr < NN) hwh[(size_t)rr * (2 * NCP) + 48 + mcol] = (unsigned short)0;
    }
}

// ============== SpMM2 + bias + log_softmax (fused epilogue) ===============
// half-wave (32 lanes) per node; hwb rows are 128 B aligned -> exactly one
// cache line per edge gather. Softmax via 32-wide shuffles, no LDS.
__global__ __launch_bounds__(256) void spmm2l_g(const int* __restrict__ rp,
                                                const uint2* __restrict__ ep,
                                                const uint* __restrict__ hwb,
                                                const float* __restrict__ b1,
                                                float2* __restrict__ out2) {
    const int n = blockIdx.x * 8 + (threadIdx.x >> 5);
    const int g = threadIdx.x & 31;
    const int beg = rp[n], end = rp[n + 1];
    float a0 = 0.f, a1 = 0.f;
    int j = beg;
    const int e8 = end - 7;
    if (j < e8) {
        uint2 e[8];
#pragma unroll
        for (int u = 0; u < 8; ++u) e[u] = ep[j + u];
        for (;;) {
            uint v[8];
#pragma unroll
            for (int u = 0; u < 8; ++u)
                v[u] = hwb[(size_t)(e[u].x & 0x1FFFFu) * NCP + g];
            float w[8];
#pragma unroll
            for (int u = 0; u < 8; ++u) w[u] = __uint_as_float(e[u].y);
            j += 8;
            const bool more = (j < e8);          // uniform within half-wave
            if (more) {
#pragma unroll
                for (int u = 0; u < 8; ++u) e[u] = ep[j + u];   // prefetch next batch
            }
#pragma unroll
            for (int u = 0; u < 8; ++u) {
                a0 = fmaf(w[u], bflo(v[u]), a0);
                a1 = fmaf(w[u], bfhi(v[u]), a1);
            }
            if (!more) break;
        }
    }
    for (; j < end; ++j) {
        const uint2 e = ep[j];
        const uint v = hwb[(size_t)(e.x & 0x1FFFFu) * NCP + g];
        const float w = __uint_as_float(e.y);
        a0 = fmaf(w, bflo(v), a0); a1 = fmaf(w, bfhi(v), a1);
    }
    float bb0 = 0.f, bb1 = 0.f;
    if (g < 20) { const float2 bb = *(const float2*)(b1 + 2 * g); bb0 = bb.x; bb1 = bb.y; }
    a0 += bb0; a1 += bb1;
    // max over the 20 active lanes (pad lanes contribute -inf / 0)
    float m = (g < 20) ? fmaxf(a0, a1) : -INFINITY;
#pragma unroll
    for (int o = 1; o < 32; o <<= 1) m = fmaxf(m, __shfl_xor(m, o, 32));
    float s = (g < 20) ? (expf(a0 - m) + expf(a1 - m)) : 0.f;
#pragma unroll
    for (int o = 1; o < 32; o <<= 1) s += __shfl_xor(s, o, 32);
    const float lse = logf(s);
    if (g < 20) out2[(size_t)n * 20 + g] = make_float2(a0 - m - lse, a1 - m - lse);
}

// ============================ launch ======================================
extern "C" void kernel_launch(void* const* d_in, const int* in_sizes, int n_in,
                              void* d_out, int out_size, void* d_ws, size_t ws_size,
                              hipStream_t stream) {
    const float* x    = (const float*)d_in[0];
    const int*   esrc = (const int*)d_in[1];
    const int*   edst = (const int*)d_in[2];
    const float* ew   = (const float*)d_in[3];
    const float* W0   = (const float*)d_in[4];
    const float* b0   = (const float*)d_in[5];
    const float* W1   = (const float*)d_in[6];
    const float* b1   = (const float*)d_in[7];
    float* out = (float*)d_out;

    // workspace layout (4-byte words); uint2/uint4 arrays at even word offsets.
    size_t o = 0;
    uint*  xwb  = (uint*)d_ws + o;  o += (size_t)NN * 64;         // 25.6 MB
    uint*  h2b  = (uint*)d_ws + o;  o += (size_t)NN * 64;         // 25.6 MB (ep1 aliases)
    uint2* ep1  = (uint2*)h2b;                                    // dead before h2b written
    uint*  hwb  = (uint*)d_ws + o;  o += (size_t)NN * NCP;        // 12.8 MB (padded rows)
    uint2* ep   = (uint2*)((uint*)d_ws + o); o += (size_t)NE * 2; // 25.6 MB
    int*   hmat = (int*)d_ws + o;   o += HTOT;                    //  1.2 MB
    int*   rp   = (int*)d_ws + o;   o += NN + 2;
    int*   partials = (int*)d_ws + o; o += 1024;
    if (o & 3) o += 4 - (o & 3);
    uint4* W0p  = (uint4*)((uint*)d_ws + o); o += 16384;          // 64 KB packed W0
    uint4* W1p  = (uint4*)((uint*)d_ws + o); o += 3072;           // 12 KB packed W1

    // 1. pack weights; xw = bf16(x @ W0) via MFMA
    prep_pack_k<<<19, 256, 0, stream>>>(W0, W1, W0p, W1p);
    gemm1_mfma<<<512, 256, 0, stream>>>(x, W0p, (unsigned short*)xwb);

    // 2. CSR build: two-pass counting sort, block-private write ranges
    p1hist_k<<<NBLK, 256, 0, stream>>>(edst, hmat);
    hscan1_k<<<HS1, 512, 0, stream>>>(hmat, partials);
    hscan2_k<<<1, 1024, 0, stream>>>(partials, HS1);
    p1scat_k<<<NBLK, 256, 0, stream>>>(esrc, edst, ew, hmat, partials, ep1);
    p2_k<<<NBUCK, 256, 0, stream>>>(hmat, partials, ep1, ep, rp);

    // 3. h2 = relu(l2norm(spmm(xw) + b0)) as bf16   (overwrites ep1 — dead)
    spmm1n_g<<<NN / 4, 256, 0, stream>>>(rp, ep, xwb, b0, h2b);
    // 4. hw = bf16(h2 @ W1) via MFMA, padded 128 B rows
    gemm2_mfma<<<NTILE, 256, 0, stream>>>(h2b, W1p, (unsigned short*)hwb);
    // 5. out = log_softmax(spmm(hw) + b1), half-wave per node
    spmm2l_g<<<NN / 8, 256, 0, stream>>>(rp, ep, hwb, b1, (float2*)out);
}